// Round 13
// baseline (104.573 us; speedup 1.0000x reference)
//
#include <hip/hip_runtime.h>
#include <math.h>

#define NROWS 4096
#define DIM   512
#define BT    64            // tile edge
#define NTILE (NROWS / BT)      // 64
#define NBLK  (NTILE * (NTILE + 1) / 2)  // 2080 triangular blocks (= 8 x 260)

typedef __attribute__((ext_vector_type(4))) float f32x4;
typedef __attribute__((ext_vector_type(8))) short bf16x8;

// ws layout (bytes):
// [0,      16384)    float mag[4096]
// [16384,  32768)    float row_neg[4096]
// [32768,  32776)    double loss
// [32776,  32780)    unsigned int pair_cnt
// [32780,  32784)    unsigned int done
// [32800,  557088)   ushort part_t[4096][64]  (bf16 negsum partials, row-major)
// [557088, 4751392)  unsigned short Xb[4096*512]  (bf16 copy of X)
// [4751392, ...)     pairs: uint2 {(i<<16)|j, float_bits(dist)}  8 B each
#define PART_OFF 32800
#define XB_OFF   (PART_OFF + NROWS * NTILE * 2)          // 557088
#define PAIR_OFF (XB_OFF + NROWS * DIM * 2)              // 4751392

__device__ inline unsigned short f2bf(float f) {
    unsigned int u = __float_as_uint(f);
    unsigned int r = (u + 0x7fffu + ((u >> 16) & 1u)) >> 16;   // RTNE
    return (unsigned short)r;
}
__device__ inline float bf2f(unsigned short u) {
    return __uint_as_float((unsigned int)u << 16);
}

// fused: bf16 convert + row sq-norms + zero the control words
__global__ void prep_kernel(const float* __restrict__ X,
                            unsigned short* __restrict__ Xb,
                            float* __restrict__ mag,
                            unsigned int* __restrict__ ctrl) {
    if (blockIdx.x == 0 && threadIdx.x < 4) ctrl[threadIdx.x] = 0u;
    int row  = blockIdx.x * 4 + (threadIdx.x >> 6);
    int lane = threadIdx.x & 63;
    const float4* p = reinterpret_cast<const float4*>(X + (size_t)row * DIM);
    short4* o = reinterpret_cast<short4*>(Xb + (size_t)row * DIM);
    float s = 0.f;
#pragma unroll
    for (int q = lane; q < DIM / 4; q += 64) {
        float4 v = p[q];
        s += v.x * v.x + v.y * v.y + v.z * v.z + v.w * v.w;
        short4 b;
        b.x = (short)f2bf(v.x); b.y = (short)f2bf(v.y);
        b.z = (short)f2bf(v.z); b.w = (short)f2bf(v.w);
        o[q] = b;
    }
#pragma unroll
    for (int off = 32; off; off >>= 1) s += __shfl_down(s, off);
    if (lane == 0) mag[row] = s;
}

// Register-direct 64x64 triangular tile, 4 waves each owning a 32x32 quadrant.
// No LDS staging, no K-loop barriers: 3-deep named register pipeline from L2.
__global__ __launch_bounds__(256, 5) void sim_mfma(
        const unsigned short* __restrict__ Xb, const int* __restrict__ tgt,
        const float* __restrict__ mag, unsigned short* __restrict__ part,
        unsigned int* __restrict__ pair_cnt, uint2* __restrict__ pairs,
        unsigned int cap) {
    __shared__ float rowbuf[2][BT];          // [wc][row-local]
    __shared__ float colbuf[2][BT];          // [wr][col-local]
    __shared__ unsigned int scan[8];

    const int tid  = threadIdx.x;
    const int lane = tid & 63;
    const int wid  = tid >> 6;        // 4 waves: 2x2 of 32x32
    const int wr   = wid >> 1, wc = wid & 1;
    const int l15  = lane & 15;
    const int lg   = lane >> 4;       // 0..3

    // XCD-aware bijective swizzle: 2080 = 8 x 260
    int b = blockIdx.x;
    int t = (b & 7) * 260 + (b >> 3);

    // triangular block mapping: t -> (bi, bj), bi <= bj (NTILE=64)
    int bi = (int)((129.0f - sqrtf(16641.0f - 8.0f * (float)t)) * 0.5f);
    if (bi < 0) bi = 0;
    if (bi > NTILE - 1) bi = NTILE - 1;
    while ((129 * (bi + 1) - (bi + 1) * (bi + 1)) / 2 <= t) bi++;
    while ((129 * bi - bi * bi) / 2 > t) bi--;
    int bj = bi + (t - (129 * bi - bi * bi) / 2);
    const int rowBase = bi * BT;
    const int colBase = bj * BT;
    const bool offd = (bi != bj);

    f32x4 acc[2][2];
#pragma unroll
    for (int m = 0; m < 2; m++)
#pragma unroll
        for (int n = 0; n < 2; n++) acc[m][n] = (f32x4){0.f, 0.f, 0.f, 0.f};

    // per-lane fragment bases: lane (lg,l15) reads 16B at row(base+l15), col k0+lg*8
    const unsigned short* pA0 = Xb + (size_t)(rowBase + wr * 32 + l15) * DIM + lg * 8;
    const unsigned short* pA1 = pA0 + 16 * DIM;
    const unsigned short* pB0 = Xb + (size_t)(colBase + wc * 32 + l15) * DIM + lg * 8;
    const unsigned short* pB1 = pB0 + 16 * DIM;

    bf16x8 av[3][2], bv[3][2];
#define LD(s, k)                                                              \
    {                                                                         \
        av[s][0] = *reinterpret_cast<const bf16x8*>(pA0 + (k) * 32);          \
        av[s][1] = *reinterpret_cast<const bf16x8*>(pA1 + (k) * 32);          \
        bv[s][0] = *reinterpret_cast<const bf16x8*>(pB0 + (k) * 32);          \
        bv[s][1] = *reinterpret_cast<const bf16x8*>(pB1 + (k) * 32);          \
    }
    LD(0, 0) LD(1, 1) LD(2, 2)
#pragma unroll
    for (int kt = 0; kt < 16; kt++) {
        const int s = kt % 3;        // static after full unroll (rule #20)
        acc[0][0] = __builtin_amdgcn_mfma_f32_16x16x32_bf16(av[s][0], bv[s][0], acc[0][0], 0, 0, 0);
        acc[0][1] = __builtin_amdgcn_mfma_f32_16x16x32_bf16(av[s][0], bv[s][1], acc[0][1], 0, 0, 0);
        acc[1][0] = __builtin_amdgcn_mfma_f32_16x16x32_bf16(av[s][1], bv[s][0], acc[1][0], 0, 0, 0);
        acc[1][1] = __builtin_amdgcn_mfma_f32_16x16x32_bf16(av[s][1], bv[s][1], acc[1][1], 0, 0, 0);
        if (kt + 3 < 16) LD(s, kt + 3)
    }
#undef LD

    // ---- fused epilogue ----
    // C/D layout: col = lane&15, row = (lane>>4)*4 + reg
    int   gcol[2], tgj[2];
    float mj[2];
#pragma unroll
    for (int n = 0; n < 2; n++) {
        gcol[n] = colBase + wc * 32 + n * 16 + l15;
        tgj[n]  = tgt[gcol[n]];
        mj[n]   = mag[gcol[n]];
    }
    int   grow[2][4], tgi[2][4];
    float mi[2][4];
#pragma unroll
    for (int m = 0; m < 2; m++)
#pragma unroll
        for (int q = 0; q < 4; q++) {
            grow[m][q] = rowBase + wr * 32 + m * 16 + lg * 4 + q;
            tgi[m][q]  = tgt[grow[m][q]];
            mi[m][q]   = mag[grow[m][q]];
        }

    float negrow[2][4];
    float negcol[2] = {0.f, 0.f};
#pragma unroll
    for (int m = 0; m < 2; m++)
#pragma unroll
        for (int q = 0; q < 4; q++) negrow[m][q] = 0.f;

    // pass A: dist (overwrites acc), negsum accumulation, positive count
    int mycnt = 0;
#pragma unroll
    for (int m = 0; m < 2; m++)
#pragma unroll
        for (int n = 0; n < 2; n++)
#pragma unroll
            for (int q = 0; q < 4; q++) {
                float d2   = mi[m][q] + mj[n] - 2.f * acc[m][n][q];
                float dist = d2 > 0.f ? sqrtf(d2) : 0.f;
                acc[m][n][q] = dist;
                bool same = (tgi[m][q] == tgj[n]);
                if (!same) {
                    if (dist != 0.f) {
                        float e = __expf(1.0f - dist);
                        negrow[m][q] += e;
                        if (offd) negcol[n] += e;
                    }
                } else if (grow[m][q] < gcol[n]) {
                    mycnt++;
                }
            }

    // row-side: reduce across the 16 l15 lanes -> rowbuf[wc][rowLocal]
#pragma unroll
    for (int m = 0; m < 2; m++)
#pragma unroll
        for (int q = 0; q < 4; q++) {
            float v = negrow[m][q];
            v += __shfl_xor(v, 1); v += __shfl_xor(v, 2);
            v += __shfl_xor(v, 4); v += __shfl_xor(v, 8);
            if (l15 == 0) rowbuf[wc][wr * 32 + m * 16 + lg * 4 + q] = v;
        }
    // col-side: reduce across the 4 lg groups -> colbuf[wr][colLocal]
#pragma unroll
    for (int n = 0; n < 2; n++) {
        float v = negcol[n];
        v += __shfl_xor(v, 16); v += __shfl_xor(v, 32);
        if (lg == 0) colbuf[wr][wc * 32 + n * 16 + l15] = v;
    }

    // pair-count scan: wave-level inclusive prefix, then block scan
    unsigned int pc = (unsigned int)mycnt;
    unsigned int incl = pc;
#pragma unroll
    for (int d = 1; d < 64; d <<= 1) {
        unsigned int tshf = __shfl_up(incl, d);
        if (lane >= d) incl += tshf;
    }
    if (lane == 63) scan[wid] = incl;
    __syncthreads();

    // collision-free transposed partial stores: part_t[row][tile]
    if (tid < BT) {
        float rv = rowbuf[0][tid] + rowbuf[1][tid];
        part[(size_t)(rowBase + tid) * NTILE + bj] = f2bf(rv);
        if (offd) {
            float cv = colbuf[0][tid] + colbuf[1][tid];
            part[(size_t)(colBase + tid) * NTILE + bi] = f2bf(cv);
        }
    }

    unsigned int woff = 0;
#pragma unroll
    for (int w = 0; w < 4; w++)
        if (w < wid) woff += scan[w];
    unsigned int btot = scan[0] + scan[1] + scan[2] + scan[3];
    if (tid == 0) scan[4] = btot ? atomicAdd(pair_cnt, btot) : 0u;
    __syncthreads();
    unsigned int mybase = scan[4] + woff + (incl - pc);

    // pass B: write pairs (dist already in acc)
    if (pc) {
        unsigned int idx = mybase;
#pragma unroll
        for (int m = 0; m < 2; m++)
#pragma unroll
            for (int n = 0; n < 2; n++)
#pragma unroll
                for (int q = 0; q < 4; q++) {
                    if (tgi[m][q] == tgj[n] && grow[m][q] < gcol[n]) {
                        if (idx < cap) {
                            uint2 e;
                            e.x = ((unsigned int)grow[m][q] << 16) | (unsigned int)gcol[n];
                            e.y = (unsigned int)__float_as_int(acc[m][n][q]);
                            pairs[idx] = e;
                        }
                        idx++;
                    }
                }
    }
}

// row_neg[r] = sum of 64 bf16 partials (contiguous 128B stripe per row)
__global__ void reduce_kernel(const unsigned short* __restrict__ part,
                              float* __restrict__ row_neg) {
    int r = blockIdx.x * 256 + threadIdx.x;
    const bf16x8* p = reinterpret_cast<const bf16x8*>(part + (size_t)r * NTILE);
    float s = 0.f;
#pragma unroll
    for (int k = 0; k < 8; k++) {
        bf16x8 a = p[k];
#pragma unroll
        for (int u = 0; u < 8; u++) s += bf2f((unsigned short)a[u]);
    }
    row_neg[r] = s;
}

// pair loss sum + fused finalize
__global__ void pair_kernel(const uint2* __restrict__ pairs,
                            const unsigned int* __restrict__ pair_cnt,
                            const float* __restrict__ row_neg,
                            unsigned int cap, double* __restrict__ loss,
                            unsigned int* __restrict__ done,
                            float* __restrict__ out) {
    __shared__ double red[256];
    unsigned int n = *pair_cnt;
    if (n > cap) n = cap;
    double local = 0.0;
    for (unsigned int p = blockIdx.x * blockDim.x + threadIdx.x; p < n;
         p += gridDim.x * blockDim.x) {
        uint2 e = pairs[p];
        int i = (int)(e.x >> 16), j = (int)(e.x & 0xffffu);
        float d = __int_as_float((int)e.y);
        float J = logf(row_neg[i] + row_neg[j]) + d;
        if (J > 0.f) local += (double)J * (double)J;
    }
    red[threadIdx.x] = local;
    __syncthreads();
    for (int s = 128; s; s >>= 1) {
        if (threadIdx.x < (unsigned)s) red[threadIdx.x] += red[threadIdx.x + s];
        __syncthreads();
    }
    if (threadIdx.x == 0) {
        atomicAdd(loss, red[0]);
        __threadfence();
        unsigned int tk = atomicAdd(done, 1u);
        if (tk == gridDim.x - 1) {
            double l = atomicAdd(loss, 0.0);   // coherent read after all adds
            out[0] = (float)(l / (2.0 * (double)(*pair_cnt)));
        }
    }
}

extern "C" void kernel_launch(void* const* d_in, const int* in_sizes, int n_in,
                              void* d_out, int out_size, void* d_ws, size_t ws_size,
                              hipStream_t stream) {
    const float* X = (const float*)d_in[0];
    const int* tgt = (const int*)d_in[1];
    float* out = (float*)d_out;

    char* ws = (char*)d_ws;
    float* mag             = (float*)(ws + 0);
    float* row_neg         = (float*)(ws + 16384);
    double* loss           = (double*)(ws + 32768);
    unsigned int* pair_cnt = (unsigned int*)(ws + 32776);
    unsigned int* done     = (unsigned int*)(ws + 32780);
    unsigned int* ctrl     = (unsigned int*)(ws + 32768);  // loss+pair_cnt+done
    unsigned short* part   = (unsigned short*)(ws + PART_OFF);
    unsigned short* Xb     = (unsigned short*)(ws + XB_OFF);
    uint2* pairs           = (uint2*)(ws + PAIR_OFF);
    unsigned int cap = 0;
    if (ws_size > PAIR_OFF + 8) cap = (unsigned int)((ws_size - PAIR_OFF) / 8);

    prep_kernel<<<NROWS / 4, 256, 0, stream>>>(X, Xb, mag, ctrl);

    sim_mfma<<<NBLK, 256, 0, stream>>>(Xb, tgt, mag, part, pair_cnt, pairs, cap);

    reduce_kernel<<<NROWS / 256, 256, 0, stream>>>(part, row_neg);

    pair_kernel<<<256, 256, 0, stream>>>(pairs, pair_cnt, row_neg, cap, loss,
                                         done, out);
}

// Round 14
// 54.951 us; speedup vs baseline: 1.9030x; 1.9030x over previous
//
#include <hip/hip_runtime.h>
#include <math.h>

#define NROWS 4096
#define DIM   512
#define BM    128
#define BK    64
#define NKT   (DIM / BK)        // 8
#define NTILE (NROWS / BM)      // 32
#define NBLK  (NTILE * (NTILE + 1) / 2)  // 528 triangular blocks (= 8 x 66)

typedef __attribute__((ext_vector_type(4))) float f32x4;
typedef __attribute__((ext_vector_type(8))) short bf16x8;

// ws layout (bytes):
// [0,      16384)    float mag[4096]
// [16384,  32768)    float row_neg[4096]
// [32768,  32776)    double loss
// [32776,  32780)    unsigned int pair_cnt
// [32780,  32784)    unsigned int done
// [32800,  294944)   ushort part_t[4096][32]  (bf16 negsum partials, row-major)
// [294944, 4489248)  unsigned short Xb[4096*512]  (bf16 copy of X)
// [4489248, ...)     pairs: uint2 {(i<<16)|j, float_bits(dist)}  8 B each
#define PART_OFF 32800
#define XB_OFF   (PART_OFF + NROWS * NTILE * 2)          // 294944
#define PAIR_OFF (XB_OFF + NROWS * DIM * 2)              // 4489248

__device__ inline unsigned short f2bf(float f) {
    unsigned int u = __float_as_uint(f);
    unsigned int r = (u + 0x7fffu + ((u >> 16) & 1u)) >> 16;   // RTNE
    return (unsigned short)r;
}
__device__ inline float bf2f(unsigned short u) {
    return __uint_as_float((unsigned int)u << 16);
}

// fused: bf16 convert + row sq-norms + zero the control words
__global__ void prep_kernel(const float* __restrict__ X,
                            unsigned short* __restrict__ Xb,
                            float* __restrict__ mag,
                            unsigned int* __restrict__ ctrl) {
    if (blockIdx.x == 0 && threadIdx.x < 4) ctrl[threadIdx.x] = 0u;
    int row  = blockIdx.x * 4 + (threadIdx.x >> 6);
    int lane = threadIdx.x & 63;
    const float4* p = reinterpret_cast<const float4*>(X + (size_t)row * DIM);
    short4* o = reinterpret_cast<short4*>(Xb + (size_t)row * DIM);
    float s = 0.f;
#pragma unroll
    for (int q = lane; q < DIM / 4; q += 64) {
        float4 v = p[q];
        s += v.x * v.x + v.y * v.y + v.z * v.z + v.w * v.w;
        short4 b;
        b.x = (short)f2bf(v.x); b.y = (short)f2bf(v.y);
        b.z = (short)f2bf(v.z); b.w = (short)f2bf(v.w);
        o[q] = b;
    }
#pragma unroll
    for (int off = 32; off; off >>= 1) s += __shfl_down(s, off);
    if (lane == 0) mag[row] = s;
}

__global__ __launch_bounds__(256, 3) void sim_mfma(
        const unsigned short* __restrict__ Xb, const int* __restrict__ tgt,
        const float* __restrict__ mag, unsigned short* __restrict__ part,
        unsigned int* __restrict__ pair_cnt, uint2* __restrict__ pairs,
        unsigned int cap) {
    __shared__ unsigned short As[BM * BK];   // 16 KB
    __shared__ unsigned short Bs[BM * BK];   // 16 KB  (32 KB total)

    const int tid  = threadIdx.x;
    const int lane = tid & 63;
    const int wid  = tid >> 6;        // 4 waves: 2x2 of 64x64
    const int wr   = wid >> 1, wc = wid & 1;
    const int l15  = lane & 15;
    const int lg   = lane >> 4;       // 0..3

    // --- L2 super-tile mapping ---
    // tiles grouped into 4x4-tile supers (512x512 rows, ~1MB working set,
    // L2-fits); supers enumerated triangular row-major; each XCD gets a
    // contiguous 66-tile run (528 = 8 x 66, bijective).
    int b = blockIdx.x;
    int g = (b & 7) * 66 + (b >> 3);
    // super-row si: C(si) = 122*si - 8*si*(si-1) cumulative tiles
    int si = 0;
#pragma unroll
    for (int r = 0; r < 7; r++)
        if (g >= 122 * (r + 1) - 8 * (r + 1) * r) si = r + 1;
    int o = g - (122 * si - 8 * si * (si - 1));
    int bi, bj;
    if (o < 10) {
        // diagonal super (si,si): triangular 4x4, row-major upper
        int ii = 0, rem = o;
#pragma unroll
        for (int r = 0; r < 3; r++)
            if (rem >= 4 - ii) { rem -= 4 - ii; ii++; }
        bi = si * 4 + ii;
        bj = si * 4 + ii + rem;
    } else {
        int o2 = o - 10;
        int sj = si + 1 + (o2 >> 4);
        int intra = o2 & 15;
        bi = si * 4 + (intra >> 2);
        bj = sj * 4 + (intra & 3);
    }
    const int rowBase = bi * BM;
    const int colBase = bj * BM;
    const bool offd = (bi != bj);

    f32x4 acc[4][4];
#pragma unroll
    for (int m = 0; m < 4; m++)
#pragma unroll
        for (int n = 0; n < 4; n++) acc[m][n] = (f32x4){0.f, 0.f, 0.f, 0.f};

    // ROLLED K-loop (small I-footprint): sync / stage / sync / compute.
    // LDS slot (row r, chunk s) holds global chunk s^(r&7) (rule #21).
#pragma unroll 1
    for (int kt = 0; kt < NKT; kt++) {
        const int k0 = kt * BK;
        __syncthreads();   // previous iteration's reads done before overwrite
#pragma unroll
        for (int c = 0; c < 4; c++) {
            int chunkBase = (c * 4 + wid) * 64;      // wave-uniform
            int idx = chunkBase + lane;              // 0..1023
            int r   = idx >> 3;
            int ch  = idx & 7;
            int gch = ch ^ (r & 7);
            const unsigned short* ga = Xb + (size_t)(rowBase + r) * DIM + k0 + gch * 8;
            __builtin_amdgcn_global_load_lds(
                (const __attribute__((address_space(1))) void*)ga,
                (__attribute__((address_space(3))) void*)(As + chunkBase * 8),
                16, 0, 0);
            const unsigned short* gb = Xb + (size_t)(colBase + r) * DIM + k0 + gch * 8;
            __builtin_amdgcn_global_load_lds(
                (const __attribute__((address_space(1))) void*)gb,
                (__attribute__((address_space(3))) void*)(Bs + chunkBase * 8),
                16, 0, 0);
        }
        __syncthreads();   // compiler drains vmcnt before barrier

#pragma unroll
        for (int ksub = 0; ksub < 2; ksub++) {
            bf16x8 af[4], bf[4];
#pragma unroll
            for (int m = 0; m < 4; m++) {
                int ra = wr * 64 + m * 16 + l15;
                int ch = (ksub * 4 + lg) ^ (ra & 7);
                af[m] = *reinterpret_cast<const bf16x8*>(&As[ra * BK + ch * 8]);
            }
#pragma unroll
            for (int n = 0; n < 4; n++) {
                int rb = wc * 64 + n * 16 + l15;
                int ch = (ksub * 4 + lg) ^ (rb & 7);
                bf[n] = *reinterpret_cast<const bf16x8*>(&Bs[rb * BK + ch * 8]);
            }
#pragma unroll
            for (int m = 0; m < 4; m++)
#pragma unroll
                for (int n = 0; n < 4; n++)
                    acc[m][n] = __builtin_amdgcn_mfma_f32_16x16x32_bf16(
                        af[m], bf[n], acc[m][n], 0, 0, 0);
        }
    }

    // ---- fused epilogue ----
    // C/D layout: col = lane&15, row = (lane>>4)*4 + reg
    int   gcol[4], tgj[4];
    float mj[4];
#pragma unroll
    for (int n = 0; n < 4; n++) {
        gcol[n] = colBase + wc * 64 + n * 16 + l15;
        tgj[n]  = tgt[gcol[n]];
        mj[n]   = mag[gcol[n]];
    }
    int   grow[4][4], tgi[4][4];
    float mi[4][4];
#pragma unroll
    for (int m = 0; m < 4; m++)
#pragma unroll
        for (int q = 0; q < 4; q++) {
            grow[m][q] = rowBase + wr * 64 + m * 16 + lg * 4 + q;
            tgi[m][q]  = tgt[grow[m][q]];
            mi[m][q]   = mag[grow[m][q]];
        }

    float negrow[4][4];
    float negcol[4] = {0.f, 0.f, 0.f, 0.f};
#pragma unroll
    for (int m = 0; m < 4; m++)
#pragma unroll
        for (int q = 0; q < 4; q++) negrow[m][q] = 0.f;

    // pass A: dist (overwrites acc), negsum accumulation, positive count
    int mycnt = 0;
#pragma unroll
    for (int m = 0; m < 4; m++)
#pragma unroll
        for (int n = 0; n < 4; n++)
#pragma unroll
            for (int q = 0; q < 4; q++) {
                float d2   = mi[m][q] + mj[n] - 2.f * acc[m][n][q];
                float dist = d2 > 0.f ? sqrtf(d2) : 0.f;
                acc[m][n][q] = dist;
                bool same = (tgi[m][q] == tgj[n]);
                if (!same) {
                    if (dist != 0.f) {
                        float e = __expf(1.0f - dist);
                        negrow[m][q] += e;
                        if (offd) negcol[n] += e;
                    }
                } else if (grow[m][q] < gcol[n]) {
                    mycnt++;
                }
            }

    __syncthreads();   // K-loop LDS reads done; overlay epilogue buffers
    float* rowbuf = (float*)&As[0];            // [2][128] floats, 1 KB
    float* colbuf = (float*)&As[1024];         // [2][128] floats, 1 KB
    unsigned int* scan = (unsigned int*)&Bs[0];

    // row-side: reduce across the 16 l15 lanes -> rowbuf[wc*128 + rowLocal]
#pragma unroll
    for (int m = 0; m < 4; m++)
#pragma unroll
        for (int q = 0; q < 4; q++) {
            float v = negrow[m][q];
            v += __shfl_xor(v, 1); v += __shfl_xor(v, 2);
            v += __shfl_xor(v, 4); v += __shfl_xor(v, 8);
            if (l15 == 0) rowbuf[wc * 128 + wr * 64 + m * 16 + lg * 4 + q] = v;
        }
    // col-side: reduce across the 4 lg groups -> colbuf[wr*128 + colLocal]
#pragma unroll
    for (int n = 0; n < 4; n++) {
        float v = negcol[n];
        v += __shfl_xor(v, 16); v += __shfl_xor(v, 32);
        if (lg == 0) colbuf[wr * 128 + wc * 64 + n * 16 + l15] = v;
    }

    // pair-count scan: wave-level inclusive prefix, then block scan
    unsigned int pc = (unsigned int)mycnt;
    unsigned int incl = pc;
#pragma unroll
    for (int d = 1; d < 64; d <<= 1) {
        unsigned int tshf = __shfl_up(incl, d);
        if (lane >= d) incl += tshf;
    }
    if (lane == 63) scan[wid] = incl;
    __syncthreads();

    // collision-free transposed partial stores: part_t[row][tile]
    if (tid < BM) {
        float rv = rowbuf[tid] + rowbuf[128 + tid];
        part[(size_t)(rowBase + tid) * NTILE + bj] = f2bf(rv);
        if (offd) {
            float cv = colbuf[tid] + colbuf[128 + tid];
            part[(size_t)(colBase + tid) * NTILE + bi] = f2bf(cv);
        }
    }

    unsigned int woff = 0;
#pragma unroll
    for (int w = 0; w < 4; w++)
        if (w < wid) woff += scan[w];
    unsigned int btot = scan[0] + scan[1] + scan[2] + scan[3];
    if (tid == 0) scan[4] = btot ? atomicAdd(pair_cnt, btot) : 0u;
    __syncthreads();
    unsigned int mybase = scan[4] + woff + (incl - pc);

    // pass B: write pairs (dist already in acc)
    if (pc) {
        unsigned int idx = mybase;
#pragma unroll
        for (int m = 0; m < 4; m++)
#pragma unroll
            for (int n = 0; n < 4; n++)
#pragma unroll
                for (int q = 0; q < 4; q++) {
                    if (tgi[m][q] == tgj[n] && grow[m][q] < gcol[n]) {
                        if (idx < cap) {
                            uint2 e;
                            e.x = ((unsigned int)grow[m][q] << 16) | (unsigned int)gcol[n];
                            e.y = (unsigned int)__float_as_int(acc[m][n][q]);
                            pairs[idx] = e;
                        }
                        idx++;
                    }
                }
    }
}

// row_neg[r] = sum of 32 bf16 partials (contiguous 64B stripe per row)
__global__ void reduce_kernel(const unsigned short* __restrict__ part,
                              float* __restrict__ row_neg) {
    int r = blockIdx.x * 256 + threadIdx.x;
    const bf16x8* p = reinterpret_cast<const bf16x8*>(part + (size_t)r * NTILE);
    float s = 0.f;
#pragma unroll
    for (int k = 0; k < 4; k++) {
        bf16x8 a = p[k];
#pragma unroll
        for (int u = 0; u < 8; u++) s += bf2f((unsigned short)a[u]);
    }
    row_neg[r] = s;
}

// pair loss sum + fused finalize
__global__ void pair_kernel(const uint2* __restrict__ pairs,
                            const unsigned int* __restrict__ pair_cnt,
                            const float* __restrict__ row_neg,
                            unsigned int cap, double* __restrict__ loss,
                            unsigned int* __restrict__ done,
                            float* __restrict__ out) {
    __shared__ double red[256];
    unsigned int n = *pair_cnt;
    if (n > cap) n = cap;
    double local = 0.0;
    for (unsigned int p = blockIdx.x * blockDim.x + threadIdx.x; p < n;
         p += gridDim.x * blockDim.x) {
        uint2 e = pairs[p];
        int i = (int)(e.x >> 16), j = (int)(e.x & 0xffffu);
        float d = __int_as_float((int)e.y);
        float J = logf(row_neg[i] + row_neg[j]) + d;
        if (J > 0.f) local += (double)J * (double)J;
    }
    red[threadIdx.x] = local;
    __syncthreads();
    for (int s = 128; s; s >>= 1) {
        if (threadIdx.x < (unsigned)s) red[threadIdx.x] += red[threadIdx.x + s];
        __syncthreads();
    }
    if (threadIdx.x == 0) {
        atomicAdd(loss, red[0]);
        __threadfence();
        unsigned int tk = atomicAdd(done, 1u);
        if (tk == gridDim.x - 1) {
            double l = atomicAdd(loss, 0.0);   // coherent read after all adds
            out[0] = (float)(l / (2.0 * (double)(*pair_cnt)));
        }
    }
}

extern "C" void kernel_launch(void* const* d_in, const int* in_sizes, int n_in,
                              void* d_out, int out_size, void* d_ws, size_t ws_size,
                              hipStream_t stream) {
    const float* X = (const float*)d_in[0];
    const int* tgt = (const int*)d_in[1];
    float* out = (float*)d_out;

    char* ws = (char*)d_ws;
    float* mag             = (float*)(ws + 0);
    float* row_neg         = (float*)(ws + 16384);
    double* loss           = (double*)(ws + 32768);
    unsigned int* pair_cnt = (unsigned int*)(ws + 32776);
    unsigned int* done     = (unsigned int*)(ws + 32780);
    unsigned int* ctrl     = (unsigned int*)(ws + 32768);  // loss+pair_cnt+done
    unsigned short* part   = (unsigned short*)(ws + PART_OFF);
    unsigned short* Xb     = (unsigned short*)(ws + XB_OFF);
    uint2* pairs           = (uint2*)(ws + PAIR_OFF);
    unsigned int cap = 0;
    if (ws_size > PAIR_OFF + 8) cap = (unsigned int)((ws_size - PAIR_OFF) / 8);

    prep_kernel<<<NROWS / 4, 256, 0, stream>>>(X, Xb, mag, ctrl);

    sim_mfma<<<NBLK, 256, 0, stream>>>(Xb, tgt, mag, part, pair_cnt, pairs, cap);

    reduce_kernel<<<NROWS / 256, 256, 0, stream>>>(part, row_neg);

    pair_kernel<<<256, 256, 0, stream>>>(pairs, pair_cnt, row_neg, cap, loss,
                                         done, out);
}